// Round 1
// baseline (237.618 us; speedup 1.0000x reference)
//
#include <hip/hip_runtime.h>
#include <hip/hip_bf16.h>
#include <math.h>

#define N_SAMPLES 262144
#define DDIM 64
#define KDIM 64
#define NROWS 128

#define LOG2PI 1.8378770664093453f
#define PRIOR_LV0 -2.0f
#define IV0 7.389056098930650f  /* exp(2.0) */

// ws layout (floats):
//   [0, 8192)      : PQ[d][128]  -> [d][0..63] = P'_kd, [d][64..127] = Q_kd
//   [8192, 8256)   : c[k]
//   [8256, 8320)   : logpi[k]

__global__ __launch_bounds__(256) void setup_kernel(
    const float* __restrict__ u_noise, const float* __restrict__ phi_logits,
    const float* __restrict__ q_mu, const float* __restrict__ q_logvar,
    const float* __restrict__ pi_logits, const float* __restrict__ prior_p,
    float* __restrict__ out, float* __restrict__ ws) {
  __shared__ float sPhi[DDIM];
  __shared__ float sR[DDIM];
  __shared__ float sBeta;
  __shared__ float sPart[4][KDIM];
  int tid = threadIdx.x;

  if (tid < 64) {  // exactly wave 0
    int d = tid;
    float u = u_noise[d];
    float g = -logf(-logf(u + 1e-9f) + 1e-9f);
    float z = (phi_logits[d] + g) / 1.0f;  // TEMPERATURE = 1.0
    float phi = 1.0f / (1.0f + expf(-z));
    sPhi[d] = phi;
    sR[d] = -0.5f * (1.0f - phi) * IV0;

    float qp = 1.0f / (1.0f + expf(-phi_logits[d]));
    qp = fminf(fmaxf(qp, 1e-6f), 1.0f - 1e-6f);
    out[1 + d] = qp;

    float betap = -0.5f * (1.0f - phi) * (LOG2PI + PRIOR_LV0);
    float pp = fminf(fmaxf(prior_p[d], 1e-6f), 1.0f - 1e-6f);
    float klp = qp * (logf(qp) - logf(pp)) +
                (1.0f - qp) * (logf(1.0f - qp) - logf(1.0f - pp));
    #pragma unroll
    for (int o = 1; o < 64; o <<= 1) {
      betap += __shfl_xor(betap, o, 64);
      klp   += __shfl_xor(klp, o, 64);
    }
    if (d == 0) {
      sBeta = betap;
      out[0] = klp * (float)N_SAMPLES;  // main kernel atomically subtracts LL
    }

    // log(softmax(pi_logits) + 1e-9), K == 64 lanes
    float l = pi_logits[d];
    float m = l;
    #pragma unroll
    for (int o = 1; o < 64; o <<= 1) m = fmaxf(m, __shfl_xor(m, o, 64));
    float e = expf(l - m);
    float s = e;
    #pragma unroll
    for (int o = 1; o < 64; o <<= 1) s += __shfl_xor(s, o, 64);
    ws[8256 + d] = logf(e / s + 1e-9f);
  }
  __syncthreads();

  int k = tid & 63, seg = tid >> 6;
  float ap = 0.0f;
  for (int dd = 0; dd < 16; ++dd) {
    int d = seg * 16 + dd;
    float lv = fminf(fmaxf(q_logvar[k * DDIM + d], -5.0f), 5.0f);
    float iv = expf(-lv);
    float a = sPhi[d] * iv;
    float mu = q_mu[k * DDIM + d];
    ws[d * 128 + k]      = -0.5f * a + sR[d];  // P'
    ws[d * 128 + 64 + k] = mu * a;             // Q
    ap += sPhi[d] * (LOG2PI + lv) + mu * mu * a;
  }
  sPart[seg][k] = ap;
  __syncthreads();
  if (tid < 64) {
    float alpha = sPart[0][tid] + sPart[1][tid] + sPart[2][tid] + sPart[3][tid];
    ws[8192 + tid] = -0.5f * alpha + sBeta;  // c_k
  }
}

__global__ __launch_bounds__(256) void gmm_main(
    const float* __restrict__ X, const float* __restrict__ ws,
    float* __restrict__ out) {
  int tid = threadIdx.x;
  int tk = tid & 15;       // k-group: columns tk*4..tk*4+3
  int tr = tid >> 4;       // row-group: rows {tr + 16j}, j=0..7
  long rowbase = (long)blockIdx.x * NROWS;
  const float* xbase = X + (rowbase + tr) * DDIM;

  float acc[8][4];
  #pragma unroll
  for (int j = 0; j < 8; ++j) {
    acc[j][0] = 0.f; acc[j][1] = 0.f; acc[j][2] = 0.f; acc[j][3] = 0.f;
  }

  for (int dc = 0; dc < DDIM; dc += 4) {
    float4 xf[8];
    #pragma unroll
    for (int j = 0; j < 8; ++j)
      xf[j] = *(const float4*)(xbase + (long)(16 * j) * DDIM + dc);
    float4 P[4], Q[4];
    #pragma unroll
    for (int i = 0; i < 4; ++i) {
      P[i] = *(const float4*)(ws + (dc + i) * 128 + tk * 4);
      Q[i] = *(const float4*)(ws + (dc + i) * 128 + 64 + tk * 4);
    }
    #pragma unroll
    for (int j = 0; j < 8; ++j) {
      float xs[4] = {xf[j].x, xf[j].y, xf[j].z, xf[j].w};
      #pragma unroll
      for (int i = 0; i < 4; ++i) {
        float x = xs[i];
        float x2 = x * x;
        acc[j][0] = fmaf(P[i].x, x2, fmaf(Q[i].x, x, acc[j][0]));
        acc[j][1] = fmaf(P[i].y, x2, fmaf(Q[i].y, x, acc[j][1]));
        acc[j][2] = fmaf(P[i].z, x2, fmaf(Q[i].z, x, acc[j][2]));
        acc[j][3] = fmaf(P[i].w, x2, fmaf(Q[i].w, x, acc[j][3]));
      }
    }
  }

  // epilogue: bias, store log_p, online LSE across the 16 lanes sharing a row
  float cb[4], lpi[4];
  #pragma unroll
  for (int kk = 0; kk < 4; ++kk) {
    cb[kk]  = ws[8192 + tk * 4 + kk];
    lpi[kk] = ws[8256 + tk * 4 + kk];
  }
  float* lpout = out + 1 + DDIM;  // float-offset 65 (16B-misaligned -> scalar stores)
  float rowacc = 0.0f;
  #pragma unroll
  for (int j = 0; j < 8; ++j) {
    long row = rowbase + tr + 16 * j;
    float o0 = acc[j][0] + cb[0];
    float o1 = acc[j][1] + cb[1];
    float o2 = acc[j][2] + cb[2];
    float o3 = acc[j][3] + cb[3];
    long off = row * KDIM + tk * 4;
    lpout[off]     = o0;
    lpout[off + 1] = o1;
    lpout[off + 2] = o2;
    lpout[off + 3] = o3;
    float v0 = o0 + lpi[0], v1 = o1 + lpi[1], v2 = o2 + lpi[2], v3 = o3 + lpi[3];
    float m = fmaxf(fmaxf(v0, v1), fmaxf(v2, v3));
    #pragma unroll
    for (int o = 1; o <= 8; o <<= 1) m = fmaxf(m, __shfl_xor(m, o, 64));
    float s = expf(v0 - m) + expf(v1 - m) + expf(v2 - m) + expf(v3 - m);
    #pragma unroll
    for (int o = 1; o <= 8; o <<= 1) s += __shfl_xor(s, o, 64);
    if (tk == 0) rowacc += m + logf(s);
  }
  // wave-level sum of the 4 row-group holders (lanes 0,16,32,48), then atomic
  float t = (tk == 0) ? rowacc : 0.0f;
  t += __shfl_xor(t, 16, 64);
  t += __shfl_xor(t, 32, 64);
  if ((tid & 63) == 0) atomicAdd(out, -t);
}

extern "C" void kernel_launch(void* const* d_in, const int* in_sizes, int n_in,
                              void* d_out, int out_size, void* d_ws, size_t ws_size,
                              hipStream_t stream) {
  const float* X           = (const float*)d_in[0];
  const float* u_noise     = (const float*)d_in[1];
  const float* phi_logits  = (const float*)d_in[2];
  const float* q_mu        = (const float*)d_in[3];
  const float* q_logvar    = (const float*)d_in[4];
  const float* pi_logits   = (const float*)d_in[5];
  const float* prior_p     = (const float*)d_in[6];
  float* out = (float*)d_out;
  float* ws  = (float*)d_ws;

  setup_kernel<<<1, 256, 0, stream>>>(u_noise, phi_logits, q_mu, q_logvar,
                                      pi_logits, prior_p, out, ws);
  gmm_main<<<N_SAMPLES / NROWS, 256, 0, stream>>>(X, ws, out);
}